// Round 1
// 204.632 us; speedup vs baseline: 1.0235x; 1.0235x over previous
//
#include <hip/hip_runtime.h>

// ws layout: NBLK rows of ROW floats each:
//   [0]=cls  [1]=noobj  [2]=S0  [3]=S1_p0  [4]=S2_p0  [5]=S1_p1  [6]=S2_p1
//   [7]=reg_p0  [8]=reg_p1  [9]=imax (int bitcast)  [10..11] pad
#define NQ      9
#define ROW     12
#define WCELLS  64              // cells per wave (wave-private staging)
#define NWAVES  4
#define TILE    (WCELLS * NWAVES)   // 256 cells per block

// Wave-private LDS staging: each wave stages its own 64 cells (7680 B) and is
// the only reader of that slice -> NO __syncthreads in the hot loop. Same-wave
// LDS RAW/WAR is ordered by in-order DS execution + compiler lgkmcnt waits.
__global__ __launch_bounds__(256) void yolo_partial_kernel(
    const float* __restrict__ pred,
    const float* __restrict__ tbox,
    const float* __restrict__ tcls,
    const int*   __restrict__ obj,
    float* __restrict__ partial,     // [gridDim.x * ROW]
    int M, int ntiles)
{
    __shared__ float sp[TILE * 30];  // 30720 B total, 7680 B per wave
    const int t    = threadIdx.x;
    const int lane = t & 63;
    const int wid  = t >> 6;
    float* spw = sp + wid * (WCELLS * 30);

    float acc[NQ];
#pragma unroll
    for (int q = 0; q < NQ; ++q) acc[q] = 0.f;
    int imax = -1;

    for (int tile = blockIdx.x; tile < ntiles; tile += gridDim.x) {
        const int c0w = tile * TILE + wid * WCELLS;  // this wave's first cell
        if (c0w >= M) continue;
        const int nc = M - c0w;

        if (nc >= WCELLS) {
            const int cell = c0w + lane;

            // ---- issue ALL global loads up front (single latency exposure) ----
            float4 tc[5];
            const float4* cv = reinterpret_cast<const float4*>(tcls + (size_t)c0w * 20);
#pragma unroll
            for (int j = 0; j < 5; ++j) tc[j] = cv[j * 64 + lane];

            const int   ov = obj[cell];
            const float4 tb = reinterpret_cast<const float4*>(tbox)[cell];  // unconditional: issues early

            // stage this wave's 64 cells: 1920 floats = 480 float4, identity copy
            const float4* pv  = reinterpret_cast<const float4*>(pred + (size_t)c0w * 30);
            float4*       spv = reinterpret_cast<float4*>(spw);
#pragma unroll
            for (int j = 0; j < 7; ++j) spv[j * 64 + lane] = pv[j * 64 + lane];
            if (lane < 32) spv[448 + lane] = pv[448 + lane];

            // ---- cls: tcls in regs vs pred ch10-29 from LDS ----
#pragma unroll
            for (int j = 0; j < 5; ++j) {
                int i  = j * 64 + lane;          // wave-local float4 index (0..319)
                int lc = i / 5;                  // local cell 0..63
                int ch = (i - lc * 5) * 4;       // 0,4,8,12,16
                const float2* s2 = reinterpret_cast<const float2*>(spw + lc * 30 + 10 + ch);
                float2 a = s2[0], b = s2[1];
                float d0 = a.x - tc[j].x, d1 = a.y - tc[j].y;
                float d2 = b.x - tc[j].z, d3 = b.y - tc[j].w;
                acc[0] += d0 * d0 + d1 * d1 + d2 * d2 + d3 * d3;
            }

            // ---- per-cell: lane owns cell c0w+lane, ch0-9 from LDS ----
            {
                const float2* s2 = reinterpret_cast<const float2*>(spw + lane * 30);
                float2 v0 = s2[0], v1 = s2[1], v2 = s2[2], v3 = s2[3], v4 = s2[4];
                // v0={x0,y0} v1={w0,h0} v2={c0,x1} v3={y1,w1} v4={h1,c1}
                const float p0c = v2.x, p1c = v4.y;
                if (ov == 0) {
                    acc[1] += p0c * p0c;         // L_NOOBJ * 2 == 1.0
                } else {
                    acc[2] += 1.f;
                    acc[3] += p0c;  acc[4] += p0c * p0c;
                    acc[5] += p1c;  acc[6] += p1c * p1c;
                    const float st2 = sqrtf(tb.z), st3 = sqrtf(tb.w);
                    float dx = v0.x - tb.x, dy = v0.y - tb.y;
                    float dw = sqrtf(v1.x) - st2, dh = sqrtf(v1.y) - st3;
                    acc[7] += dx * dx + dy * dy + dw * dw + dh * dh;
                    dx = v2.y - tb.x;           dy = v3.x - tb.y;
                    dw = sqrtf(v3.y) - st2;     dh = sqrtf(v4.x) - st3;
                    acc[8] += dx * dx + dy * dy + dw * dw + dh * dh;
                    imax = cell;
                }
            }
        } else if (lane < nc) {
            // ---- tail (not hit when M % 256 == 0): direct global, correctness-only ----
            const int cell = c0w + lane;
            const float* p   = pred + (size_t)cell * 30;
            const float* tcl = tcls + (size_t)cell * 20;
#pragma unroll
            for (int ch = 0; ch < 20; ++ch) {
                float d = p[10 + ch] - tcl[ch];
                acc[0] += d * d;
            }
            const int ov = obj[cell];
            const float p0c = p[4], p1c = p[9];
            if (ov == 0) {
                acc[1] += p0c * p0c;
            } else {
                const float* tb = tbox + (size_t)cell * 4;
                acc[2] += 1.f;
                acc[3] += p0c;  acc[4] += p0c * p0c;
                acc[5] += p1c;  acc[6] += p1c * p1c;
                const float st2 = sqrtf(tb[2]), st3 = sqrtf(tb[3]);
                float dx = p[0] - tb[0], dy = p[1] - tb[1];
                float dw = sqrtf(p[2]) - st2, dh = sqrtf(p[3]) - st3;
                acc[7] += dx * dx + dy * dy + dw * dw + dh * dh;
                dx = p[5] - tb[0]; dy = p[6] - tb[1];
                dw = sqrtf(p[7]) - st2; dh = sqrtf(p[8]) - st3;
                acc[8] += dx * dx + dy * dy + dw * dw + dh * dh;
                imax = cell;
            }
        }
    }

    // ---- wave (64-lane) shuffle reduction ----
#pragma unroll
    for (int off = 32; off > 0; off >>= 1) {
#pragma unroll
        for (int q = 0; q < NQ; ++q) acc[q] += __shfl_down(acc[q], off, 64);
        imax = max(imax, __shfl_down(imax, off, 64));
    }

    __shared__ float sred[4][NQ];
    __shared__ int   sidx[4];
    if (lane == 0) {
#pragma unroll
        for (int q = 0; q < NQ; ++q) sred[wid][q] = acc[q];
        sidx[wid] = imax;
    }
    __syncthreads();   // only barrier in the kernel: final cross-wave reduce

    if (t == 0) {
        float tot[NQ];
        int   mx = sidx[0];
#pragma unroll
        for (int q = 0; q < NQ; ++q) tot[q] = sred[0][q];
        for (int w = 1; w < 4; ++w) {
#pragma unroll
            for (int q = 0; q < NQ; ++q) tot[q] += sred[w][q];
            mx = max(mx, sidx[w]);
        }
        float* row = partial + (size_t)blockIdx.x * ROW;
#pragma unroll
        for (int q = 0; q < NQ; ++q) row[q] = tot[q];
        reinterpret_cast<int*>(row)[NQ] = mx;
    }
}

__global__ __launch_bounds__(256) void yolo_final_kernel(
    const float* __restrict__ pred,
    const float* __restrict__ tbox,
    const float* __restrict__ partial,
    float* __restrict__ out,
    int nrows, float invN)
{
    const int t = threadIdx.x;
    float acc[NQ];
#pragma unroll
    for (int q = 0; q < NQ; ++q) acc[q] = 0.f;
    int imax = -1;

    for (int r = t; r < nrows; r += 256) {
        const float* row = partial + (size_t)r * ROW;
#pragma unroll
        for (int q = 0; q < NQ; ++q) acc[q] += row[q];
        imax = max(imax, reinterpret_cast<const int*>(row)[NQ]);
    }

#pragma unroll
    for (int off = 32; off > 0; off >>= 1) {
#pragma unroll
        for (int q = 0; q < NQ; ++q) acc[q] += __shfl_down(acc[q], off, 64);
        imax = max(imax, __shfl_down(imax, off, 64));
    }

    __shared__ float sred[4][NQ];
    __shared__ int   sidx[4];
    const int lane = t & 63;
    const int wid  = t >> 6;
    if (lane == 0) {
#pragma unroll
        for (int q = 0; q < NQ; ++q) sred[wid][q] = acc[q];
        sidx[wid] = imax;
    }
    __syncthreads();

    if (t == 0) {
        float sums[NQ];
        int idx = sidx[0];
#pragma unroll
        for (int q = 0; q < NQ; ++q) sums[q] = sred[0][q];
        for (int w = 1; w < 4; ++w) {
#pragma unroll
            for (int q = 0; q < NQ; ++q) sums[q] += sred[w][q];
            idx = max(idx, sidx[w]);
        }

        const float* p  = pred + (size_t)idx * 30;
        const float* tb = tbox + (size_t)idx * 4;

        float b0[4], b1[4], bt[4];
        {
            float cx = p[0] / 14.f, cy = p[1] / 14.f;
            b0[0] = cx - 0.5f * p[2]; b0[1] = cy - 0.5f * p[3];
            b0[2] = cx + 0.5f * p[2]; b0[3] = cy + 0.5f * p[3];
        }
        {
            float cx = p[5] / 14.f, cy = p[6] / 14.f;
            b1[0] = cx - 0.5f * p[7]; b1[1] = cy - 0.5f * p[8];
            b1[2] = cx + 0.5f * p[7]; b1[3] = cy + 0.5f * p[8];
        }
        {
            float cx = tb[0] / 14.f, cy = tb[1] / 14.f;
            bt[0] = cx - 0.5f * tb[2]; bt[1] = cy - 0.5f * tb[3];
            bt[2] = cx + 0.5f * tb[2]; bt[3] = cy + 0.5f * tb[3];
        }
        auto iou = [](const float* a, const float* b) {
            float ltx = fmaxf(a[0], b[0]), lty = fmaxf(a[1], b[1]);
            float rbx = fminf(a[2], b[2]), rby = fminf(a[3], b[3]);
            float w = fmaxf(rbx - ltx, 0.f), h = fmaxf(rby - lty, 0.f);
            float inter = w * h;
            float a1 = (a[2] - a[0]) * (a[3] - a[1]);
            float a2 = (b[2] - b[0]) * (b[3] - b[1]);
            return inter / (a1 + a2 - inter);
        };
        float iou0 = iou(b0, bt), iou1 = iou(b1, bt);
        bool  m = iou0 > iou1;
        float c = m ? iou0 : iou1;

        float S0  = sums[2];
        float S1  = m ? sums[3] : sums[5];
        float S2  = m ? sums[4] : sums[6];
        float reg = m ? sums[7] : sums[8];

        float reg_loss   = 5.f * reg;                       // L_COORD
        float containing = S2 - 2.f * c * S1 + c * c * S0;  // sum obj*(conf-c)^2
        float noobj      = sums[1];
        float cls        = sums[0];
        float total      = cls + noobj + reg_loss + containing;

        out[0] = total * invN;
        out[1] = reg_loss * invN;
        out[2] = containing * invN;
        out[3] = noobj * invN;
        out[4] = cls * invN;
    }
}

extern "C" void kernel_launch(void* const* d_in, const int* in_sizes, int n_in,
                              void* d_out, int out_size, void* d_ws, size_t ws_size,
                              hipStream_t stream) {
    const float* pred = (const float*)d_in[0];
    const float* tbox = (const float*)d_in[1];
    const float* tcls = (const float*)d_in[2];
    const int*   obj  = (const int*)d_in[3];
    float* out = (float*)d_out;

    const int M = in_sizes[3];                  // BATCH * S * S
    const int N = in_sizes[0] / (14 * 14 * 30); // BATCH

    const int ntiles = (M + TILE - 1) / TILE;   // 3136 at M=802816

    // one private partial row per block; no atomics, no memset needed
    int nblk = ntiles;                          // 1 tile per block
    const int max_rows = (int)(ws_size / (ROW * sizeof(float)));
    if (nblk > max_rows) nblk = max_rows;
    if (nblk < 1) nblk = 1;

    float* partial = (float*)d_ws;

    yolo_partial_kernel<<<nblk, 256, 0, stream>>>(pred, tbox, tcls, obj, partial, M, ntiles);
    yolo_final_kernel<<<1, 256, 0, stream>>>(pred, tbox, partial, out, nblk, 1.f / (float)N);
}

// Round 2
// 203.809 us; speedup vs baseline: 1.0277x; 1.0040x over previous
//
#include <hip/hip_runtime.h>

// ws layout: NBLK rows of ROW floats each:
//   [0]=cls  [1]=noobj  [2]=S0  [3]=S1_p0  [4]=S2_p0  [5]=S1_p1  [6]=S2_p1
//   [7]=reg_p0  [8]=reg_p1  [9]=imax (int bitcast)  [10..11] pad
#define NQ      9
#define ROW     12
#define TILE    256

// LDS-free design: no staging, no transpose, no hot-loop barriers.
// cls phase reads pred ch10-29 as gappy-monotonic float2 streams (L1-coalesced);
// per-cell phase reads pred ch0-9 per-lane from the SAME cache lines (L1/L2-warm,
// every ch0-9 byte shares a 64B line with a ch10-15 byte). Each pred line is
// fetched from HBM exactly once. Occupancy is VGPR-bound, not LDS-bound.
__global__ __launch_bounds__(256) void yolo_partial_kernel(
    const float* __restrict__ pred,
    const float* __restrict__ tbox,
    const float* __restrict__ tcls,
    const int*   __restrict__ obj,
    float* __restrict__ partial,     // [gridDim.x * ROW]
    int M, int ntiles)
{
    const int t = threadIdx.x;

    float acc[NQ];
#pragma unroll
    for (int q = 0; q < NQ; ++q) acc[q] = 0.f;
    int imax = -1;

    for (int tile = blockIdx.x; tile < ntiles; tile += gridDim.x) {
        const int c0 = tile * TILE;
        const int nc = min(TILE, M - c0);

        if (nc == TILE) {
            const int cell = c0 + t;
            const float* pb = pred + (size_t)c0 * 30;

            // ---- issue per-cell loads first (independent, in flight across cls) ----
            const int    ov = obj[cell];
            const float4 tb = reinterpret_cast<const float4*>(tbox)[cell];
            const float2* pc2 = reinterpret_cast<const float2*>(pred + (size_t)cell * 30);
            const float2 v0 = pc2[0], v1 = pc2[1], v2 = pc2[2], v3 = pc2[3], v4 = pc2[4];

            // ---- cls: tcls coalesced float4, pred ch10-29 gappy float2 ----
            const float4* cv = reinterpret_cast<const float4*>(tcls + (size_t)c0 * 20);
#pragma unroll
            for (int j = 0; j < 5; ++j) {
                const int i = j * 256 + t;               // float4 index, 0..1279
                const float4 v = cv[i];
                const unsigned lc = (unsigned)i / 5u;    // cell within tile (magic mul)
                const int ch = (i - (int)lc * 5) * 4;    // 0,4,8,12,16
                const float2* s2 = reinterpret_cast<const float2*>(pb + lc * 30 + 10 + ch);
                const float2 a = s2[0], b = s2[1];
                float d0 = a.x - v.x, d1 = a.y - v.y;
                float d2 = b.x - v.z, d3 = b.y - v.w;
                acc[0] += d0 * d0 + d1 * d1 + d2 * d2 + d3 * d3;
            }

            // ---- per-cell: lane owns cell c0+t ----
            {
                // v0={x0,y0} v1={w0,h0} v2={c0,x1} v3={y1,w1} v4={h1,c1}
                const float p0c = v2.x, p1c = v4.y;
                if (ov == 0) {
                    acc[1] += p0c * p0c;                 // L_NOOBJ * 2 == 1.0
                } else {
                    acc[2] += 1.f;
                    acc[3] += p0c;  acc[4] += p0c * p0c;
                    acc[5] += p1c;  acc[6] += p1c * p1c;
                    const float st2 = sqrtf(tb.z), st3 = sqrtf(tb.w);
                    float dx = v0.x - tb.x, dy = v0.y - tb.y;
                    float dw = sqrtf(v1.x) - st2, dh = sqrtf(v1.y) - st3;
                    acc[7] += dx * dx + dy * dy + dw * dw + dh * dh;
                    dx = v2.y - tb.x;           dy = v3.x - tb.y;
                    dw = sqrtf(v3.y) - st2;     dh = sqrtf(v4.x) - st3;
                    acc[8] += dx * dx + dy * dy + dw * dw + dh * dh;
                    imax = cell;
                }
            }
        } else if (t < nc) {
            // ---- tail (not hit when M % 256 == 0): scalar, correctness-only ----
            const int cell = c0 + t;
            const float* p   = pred + (size_t)cell * 30;
            const float* tcl = tcls + (size_t)cell * 20;
#pragma unroll
            for (int ch = 0; ch < 20; ++ch) {
                float d = p[10 + ch] - tcl[ch];
                acc[0] += d * d;
            }
            const int ov = obj[cell];
            const float p0c = p[4], p1c = p[9];
            if (ov == 0) {
                acc[1] += p0c * p0c;
            } else {
                const float* tb = tbox + (size_t)cell * 4;
                acc[2] += 1.f;
                acc[3] += p0c;  acc[4] += p0c * p0c;
                acc[5] += p1c;  acc[6] += p1c * p1c;
                const float st2 = sqrtf(tb[2]), st3 = sqrtf(tb[3]);
                float dx = p[0] - tb[0], dy = p[1] - tb[1];
                float dw = sqrtf(p[2]) - st2, dh = sqrtf(p[3]) - st3;
                acc[7] += dx * dx + dy * dy + dw * dw + dh * dh;
                dx = p[5] - tb[0]; dy = p[6] - tb[1];
                dw = sqrtf(p[7]) - st2; dh = sqrtf(p[8]) - st3;
                acc[8] += dx * dx + dy * dy + dw * dw + dh * dh;
                imax = cell;
            }
        }
    }

    // ---- wave (64-lane) shuffle reduction ----
#pragma unroll
    for (int off = 32; off > 0; off >>= 1) {
#pragma unroll
        for (int q = 0; q < NQ; ++q) acc[q] += __shfl_down(acc[q], off, 64);
        imax = max(imax, __shfl_down(imax, off, 64));
    }

    __shared__ float sred[4][NQ];
    __shared__ int   sidx[4];
    const int lane = t & 63;
    const int wid  = t >> 6;
    if (lane == 0) {
#pragma unroll
        for (int q = 0; q < NQ; ++q) sred[wid][q] = acc[q];
        sidx[wid] = imax;
    }
    __syncthreads();

    if (t == 0) {
        float tot[NQ];
        int   mx = sidx[0];
#pragma unroll
        for (int q = 0; q < NQ; ++q) tot[q] = sred[0][q];
        for (int w = 1; w < 4; ++w) {
#pragma unroll
            for (int q = 0; q < NQ; ++q) tot[q] += sred[w][q];
            mx = max(mx, sidx[w]);
        }
        float* row = partial + (size_t)blockIdx.x * ROW;
#pragma unroll
        for (int q = 0; q < NQ; ++q) row[q] = tot[q];
        reinterpret_cast<int*>(row)[NQ] = mx;
    }
}

__global__ __launch_bounds__(256) void yolo_final_kernel(
    const float* __restrict__ pred,
    const float* __restrict__ tbox,
    const float* __restrict__ partial,
    float* __restrict__ out,
    int nrows, float invN)
{
    const int t = threadIdx.x;
    float acc[NQ];
#pragma unroll
    for (int q = 0; q < NQ; ++q) acc[q] = 0.f;
    int imax = -1;

    for (int r = t; r < nrows; r += 256) {
        const float* row = partial + (size_t)r * ROW;
#pragma unroll
        for (int q = 0; q < NQ; ++q) acc[q] += row[q];
        imax = max(imax, reinterpret_cast<const int*>(row)[NQ]);
    }

#pragma unroll
    for (int off = 32; off > 0; off >>= 1) {
#pragma unroll
        for (int q = 0; q < NQ; ++q) acc[q] += __shfl_down(acc[q], off, 64);
        imax = max(imax, __shfl_down(imax, off, 64));
    }

    __shared__ float sred[4][NQ];
    __shared__ int   sidx[4];
    const int lane = t & 63;
    const int wid  = t >> 6;
    if (lane == 0) {
#pragma unroll
        for (int q = 0; q < NQ; ++q) sred[wid][q] = acc[q];
        sidx[wid] = imax;
    }
    __syncthreads();

    if (t == 0) {
        float sums[NQ];
        int idx = sidx[0];
#pragma unroll
        for (int q = 0; q < NQ; ++q) sums[q] = sred[0][q];
        for (int w = 1; w < 4; ++w) {
#pragma unroll
            for (int q = 0; q < NQ; ++q) sums[q] += sred[w][q];
            idx = max(idx, sidx[w]);
        }

        const float* p  = pred + (size_t)idx * 30;
        const float* tb = tbox + (size_t)idx * 4;

        float b0[4], b1[4], bt[4];
        {
            float cx = p[0] / 14.f, cy = p[1] / 14.f;
            b0[0] = cx - 0.5f * p[2]; b0[1] = cy - 0.5f * p[3];
            b0[2] = cx + 0.5f * p[2]; b0[3] = cy + 0.5f * p[3];
        }
        {
            float cx = p[5] / 14.f, cy = p[6] / 14.f;
            b1[0] = cx - 0.5f * p[7]; b1[1] = cy - 0.5f * p[8];
            b1[2] = cx + 0.5f * p[7]; b1[3] = cy + 0.5f * p[8];
        }
        {
            float cx = tb[0] / 14.f, cy = tb[1] / 14.f;
            bt[0] = cx - 0.5f * tb[2]; bt[1] = cy - 0.5f * tb[3];
            bt[2] = cx + 0.5f * tb[2]; bt[3] = cy + 0.5f * tb[3];
        }
        auto iou = [](const float* a, const float* b) {
            float ltx = fmaxf(a[0], b[0]), lty = fmaxf(a[1], b[1]);
            float rbx = fminf(a[2], b[2]), rby = fminf(a[3], b[3]);
            float w = fmaxf(rbx - ltx, 0.f), h = fmaxf(rby - lty, 0.f);
            float inter = w * h;
            float a1 = (a[2] - a[0]) * (a[3] - a[1]);
            float a2 = (b[2] - b[0]) * (b[3] - b[1]);
            return inter / (a1 + a2 - inter);
        };
        float iou0 = iou(b0, bt), iou1 = iou(b1, bt);
        bool  m = iou0 > iou1;
        float c = m ? iou0 : iou1;

        float S0  = sums[2];
        float S1  = m ? sums[3] : sums[5];
        float S2  = m ? sums[4] : sums[6];
        float reg = m ? sums[7] : sums[8];

        float reg_loss   = 5.f * reg;                       // L_COORD
        float containing = S2 - 2.f * c * S1 + c * c * S0;  // sum obj*(conf-c)^2
        float noobj      = sums[1];
        float cls        = sums[0];
        float total      = cls + noobj + reg_loss + containing;

        out[0] = total * invN;
        out[1] = reg_loss * invN;
        out[2] = containing * invN;
        out[3] = noobj * invN;
        out[4] = cls * invN;
    }
}

extern "C" void kernel_launch(void* const* d_in, const int* in_sizes, int n_in,
                              void* d_out, int out_size, void* d_ws, size_t ws_size,
                              hipStream_t stream) {
    const float* pred = (const float*)d_in[0];
    const float* tbox = (const float*)d_in[1];
    const float* tcls = (const float*)d_in[2];
    const int*   obj  = (const int*)d_in[3];
    float* out = (float*)d_out;

    const int M = in_sizes[3];                  // BATCH * S * S
    const int N = in_sizes[0] / (14 * 14 * 30); // BATCH

    const int ntiles = (M + TILE - 1) / TILE;   // 3136 at M=802816

    int nblk = ntiles;                          // 1 tile per block when ws allows
    const int max_rows = (int)(ws_size / (ROW * sizeof(float)));
    if (nblk > max_rows) nblk = max_rows;
    if (nblk < 1) nblk = 1;

    float* partial = (float*)d_ws;

    yolo_partial_kernel<<<nblk, 256, 0, stream>>>(pred, tbox, tcls, obj, partial, M, ntiles);
    yolo_final_kernel<<<1, 256, 0, stream>>>(pred, tbox, partial, out, nblk, 1.f / (float)N);
}

// Round 3
// 203.739 us; speedup vs baseline: 1.0280x; 1.0003x over previous
//
#include <hip/hip_runtime.h>

// ws layout: NBLK rows of ROW floats each:
//   [0]=cls  [1]=noobj  [2]=S0  [3]=S1_p0  [4]=S2_p0  [5]=S1_p1  [6]=S2_p1
//   [7]=reg_p0  [8]=reg_p1  [9]=imax (int bitcast)  [10..11] pad
#define NQ      9
#define ROW     12
#define TILE    256
#define NBLK    768

// Register double-buffered software pipeline: while computing tile A, tile B's
// full load burst is in flight (counted vmcnt waits). Keeps each wave's
// outstanding-byte count high continuously instead of drain-then-compute.
// All array indices are compile-time constants after full unroll (no scratch).
struct TileRegs {
    float4 tc[5];          // tcls, coalesced float4
    float2 pa[5], pb[5];   // pred ch10-29, gappy-monotonic float2 pairs
    float2 v0, v1, v2, v3, v4;  // own cell pred ch0-9
    float4 tb;             // own cell tbox
    int    ov;             // own cell obj
};

__device__ __forceinline__ void load_tile(TileRegs& R, int c0, int t,
    const float* __restrict__ pred, const float* __restrict__ tbox,
    const float* __restrict__ tcls, const int* __restrict__ obj)
{
    const int cell = c0 + t;
    const float4* cv = reinterpret_cast<const float4*>(tcls + (size_t)c0 * 20);
    const float*  pb_ = pred + (size_t)c0 * 30;
#pragma unroll
    for (int j = 0; j < 5; ++j) {
        const int i = j * 256 + t;                 // float4 index, 0..1279
        R.tc[j] = cv[i];
        const unsigned lc = (unsigned)i / 5u;      // cell within tile
        const int ch = (i - (int)lc * 5) * 4;      // 0,4,8,12,16
        const float2* s2 = reinterpret_cast<const float2*>(pb_ + lc * 30 + 10 + ch);
        R.pa[j] = s2[0];
        R.pb[j] = s2[1];
    }
    const float2* pc2 = reinterpret_cast<const float2*>(pred + (size_t)cell * 30);
    R.v0 = pc2[0]; R.v1 = pc2[1]; R.v2 = pc2[2]; R.v3 = pc2[3]; R.v4 = pc2[4];
    R.tb = reinterpret_cast<const float4*>(tbox)[cell];
    R.ov = obj[cell];
}

__device__ __forceinline__ void compute_tile(const TileRegs& R, float acc[NQ],
                                             int& imax, int c0, int t)
{
#pragma unroll
    for (int j = 0; j < 5; ++j) {
        float d0 = R.pa[j].x - R.tc[j].x, d1 = R.pa[j].y - R.tc[j].y;
        float d2 = R.pb[j].x - R.tc[j].z, d3 = R.pb[j].y - R.tc[j].w;
        acc[0] += d0 * d0 + d1 * d1 + d2 * d2 + d3 * d3;
    }
    // v0={x0,y0} v1={w0,h0} v2={c0,x1} v3={y1,w1} v4={h1,c1}
    const float p0c = R.v2.x, p1c = R.v4.y;
    if (R.ov == 0) {
        acc[1] += p0c * p0c;                       // L_NOOBJ * 2 == 1.0
    } else {
        acc[2] += 1.f;
        acc[3] += p0c;  acc[4] += p0c * p0c;
        acc[5] += p1c;  acc[6] += p1c * p1c;
        const float st2 = sqrtf(R.tb.z), st3 = sqrtf(R.tb.w);
        float dx = R.v0.x - R.tb.x, dy = R.v0.y - R.tb.y;
        float dw = sqrtf(R.v1.x) - st2, dh = sqrtf(R.v1.y) - st3;
        acc[7] += dx * dx + dy * dy + dw * dw + dh * dh;
        dx = R.v2.y - R.tb.x;        dy = R.v3.x - R.tb.y;
        dw = sqrtf(R.v3.y) - st2;    dh = sqrtf(R.v4.x) - st3;
        acc[8] += dx * dx + dy * dy + dw * dw + dh * dh;
        imax = c0 + t;
    }
}

__global__ __launch_bounds__(256, 3) void yolo_partial_kernel(
    const float* __restrict__ pred,
    const float* __restrict__ tbox,
    const float* __restrict__ tcls,
    const int*   __restrict__ obj,
    float* __restrict__ partial,     // [gridDim.x * ROW]
    int M, int ntiles)
{
    const int t = threadIdx.x;
    const int G = gridDim.x;

    float acc[NQ];
#pragma unroll
    for (int q = 0; q < NQ; ++q) acc[q] = 0.f;
    int imax = -1;

    const int nfull = M / TILE;      // tiles with all 256 cells present

    // ---- software-pipelined loop over this block's full tiles ----
    int ta = blockIdx.x;
    if (ta < nfull) {
        TileRegs A, B;
        load_tile(A, ta * TILE, t, pred, tbox, tcls, obj);
        for (;;) {
            const int tbn = ta + G;
            const bool hb = tbn < nfull;
            if (hb) load_tile(B, tbn * TILE, t, pred, tbox, tcls, obj);
            compute_tile(A, acc, imax, ta * TILE, t);
            if (!hb) break;
            const int tan = tbn + G;
            const bool ha = tan < nfull;
            if (ha) load_tile(A, tan * TILE, t, pred, tbox, tcls, obj);
            compute_tile(B, acc, imax, tbn * TILE, t);
            if (!ha) break;
            ta = tan;
        }
    }

    // ---- tail tile (only if M % TILE != 0): scalar, correctness-only ----
    const int rem = M - nfull * TILE;
    if (rem > 0 && (nfull % G) == blockIdx.x && t < rem) {
        const int cell = nfull * TILE + t;
        const float* p   = pred + (size_t)cell * 30;
        const float* tcl = tcls + (size_t)cell * 20;
#pragma unroll
        for (int ch = 0; ch < 20; ++ch) {
            float d = p[10 + ch] - tcl[ch];
            acc[0] += d * d;
        }
        const int ov = obj[cell];
        const float p0c = p[4], p1c = p[9];
        if (ov == 0) {
            acc[1] += p0c * p0c;
        } else {
            const float* tb = tbox + (size_t)cell * 4;
            acc[2] += 1.f;
            acc[3] += p0c;  acc[4] += p0c * p0c;
            acc[5] += p1c;  acc[6] += p1c * p1c;
            const float st2 = sqrtf(tb[2]), st3 = sqrtf(tb[3]);
            float dx = p[0] - tb[0], dy = p[1] - tb[1];
            float dw = sqrtf(p[2]) - st2, dh = sqrtf(p[3]) - st3;
            acc[7] += dx * dx + dy * dy + dw * dw + dh * dh;
            dx = p[5] - tb[0]; dy = p[6] - tb[1];
            dw = sqrtf(p[7]) - st2; dh = sqrtf(p[8]) - st3;
            acc[8] += dx * dx + dy * dy + dw * dw + dh * dh;
            imax = cell;
        }
    }

    // ---- wave (64-lane) shuffle reduction ----
#pragma unroll
    for (int off = 32; off > 0; off >>= 1) {
#pragma unroll
        for (int q = 0; q < NQ; ++q) acc[q] += __shfl_down(acc[q], off, 64);
        imax = max(imax, __shfl_down(imax, off, 64));
    }

    __shared__ float sred[4][NQ];
    __shared__ int   sidx[4];
    const int lane = t & 63;
    const int wid  = t >> 6;
    if (lane == 0) {
#pragma unroll
        for (int q = 0; q < NQ; ++q) sred[wid][q] = acc[q];
        sidx[wid] = imax;
    }
    __syncthreads();

    if (t == 0) {
        float tot[NQ];
        int   mx = sidx[0];
#pragma unroll
        for (int q = 0; q < NQ; ++q) tot[q] = sred[0][q];
        for (int w = 1; w < 4; ++w) {
#pragma unroll
            for (int q = 0; q < NQ; ++q) tot[q] += sred[w][q];
            mx = max(mx, sidx[w]);
        }
        float* row = partial + (size_t)blockIdx.x * ROW;
#pragma unroll
        for (int q = 0; q < NQ; ++q) row[q] = tot[q];
        reinterpret_cast<int*>(row)[NQ] = mx;
    }
}

__global__ __launch_bounds__(256) void yolo_final_kernel(
    const float* __restrict__ pred,
    const float* __restrict__ tbox,
    const float* __restrict__ partial,
    float* __restrict__ out,
    int nrows, float invN)
{
    const int t = threadIdx.x;
    float acc[NQ];
#pragma unroll
    for (int q = 0; q < NQ; ++q) acc[q] = 0.f;
    int imax = -1;

    for (int r = t; r < nrows; r += 256) {
        const float* row = partial + (size_t)r * ROW;
#pragma unroll
        for (int q = 0; q < NQ; ++q) acc[q] += row[q];
        imax = max(imax, reinterpret_cast<const int*>(row)[NQ]);
    }

#pragma unroll
    for (int off = 32; off > 0; off >>= 1) {
#pragma unroll
        for (int q = 0; q < NQ; ++q) acc[q] += __shfl_down(acc[q], off, 64);
        imax = max(imax, __shfl_down(imax, off, 64));
    }

    __shared__ float sred[4][NQ];
    __shared__ int   sidx[4];
    const int lane = t & 63;
    const int wid  = t >> 6;
    if (lane == 0) {
#pragma unroll
        for (int q = 0; q < NQ; ++q) sred[wid][q] = acc[q];
        sidx[wid] = imax;
    }
    __syncthreads();

    if (t == 0) {
        float sums[NQ];
        int idx = sidx[0];
#pragma unroll
        for (int q = 0; q < NQ; ++q) sums[q] = sred[0][q];
        for (int w = 1; w < 4; ++w) {
#pragma unroll
            for (int q = 0; q < NQ; ++q) sums[q] += sred[w][q];
            idx = max(idx, sidx[w]);
        }

        const float* p  = pred + (size_t)idx * 30;
        const float* tb = tbox + (size_t)idx * 4;

        float b0[4], b1[4], bt[4];
        {
            float cx = p[0] / 14.f, cy = p[1] / 14.f;
            b0[0] = cx - 0.5f * p[2]; b0[1] = cy - 0.5f * p[3];
            b0[2] = cx + 0.5f * p[2]; b0[3] = cy + 0.5f * p[3];
        }
        {
            float cx = p[5] / 14.f, cy = p[6] / 14.f;
            b1[0] = cx - 0.5f * p[7]; b1[1] = cy - 0.5f * p[8];
            b1[2] = cx + 0.5f * p[7]; b1[3] = cy + 0.5f * p[8];
        }
        {
            float cx = tb[0] / 14.f, cy = tb[1] / 14.f;
            bt[0] = cx - 0.5f * tb[2]; bt[1] = cy - 0.5f * tb[3];
            bt[2] = cx + 0.5f * tb[2]; bt[3] = cy + 0.5f * tb[3];
        }
        auto iou = [](const float* a, const float* b) {
            float ltx = fmaxf(a[0], b[0]), lty = fmaxf(a[1], b[1]);
            float rbx = fminf(a[2], b[2]), rby = fminf(a[3], b[3]);
            float w = fmaxf(rbx - ltx, 0.f), h = fmaxf(rby - lty, 0.f);
            float inter = w * h;
            float a1 = (a[2] - a[0]) * (a[3] - a[1]);
            float a2 = (b[2] - b[0]) * (b[3] - b[1]);
            return inter / (a1 + a2 - inter);
        };
        float iou0 = iou(b0, bt), iou1 = iou(b1, bt);
        bool  m = iou0 > iou1;
        float c = m ? iou0 : iou1;

        float S0  = sums[2];
        float S1  = m ? sums[3] : sums[5];
        float S2  = m ? sums[4] : sums[6];
        float reg = m ? sums[7] : sums[8];

        float reg_loss   = 5.f * reg;                       // L_COORD
        float containing = S2 - 2.f * c * S1 + c * c * S0;  // sum obj*(conf-c)^2
        float noobj      = sums[1];
        float cls        = sums[0];
        float total      = cls + noobj + reg_loss + containing;

        out[0] = total * invN;
        out[1] = reg_loss * invN;
        out[2] = containing * invN;
        out[3] = noobj * invN;
        out[4] = cls * invN;
    }
}

extern "C" void kernel_launch(void* const* d_in, const int* in_sizes, int n_in,
                              void* d_out, int out_size, void* d_ws, size_t ws_size,
                              hipStream_t stream) {
    const float* pred = (const float*)d_in[0];
    const float* tbox = (const float*)d_in[1];
    const float* tcls = (const float*)d_in[2];
    const int*   obj  = (const int*)d_in[3];
    float* out = (float*)d_out;

    const int M = in_sizes[3];                  // BATCH * S * S
    const int N = in_sizes[0] / (14 * 14 * 30); // BATCH

    const int ntiles = (M + TILE - 1) / TILE;   // 3136 at M=802816

    int nblk = NBLK;                            // 3 blocks/CU, single generation
    if (nblk > ntiles) nblk = ntiles;
    const int max_rows = (int)(ws_size / (ROW * sizeof(float)));
    if (nblk > max_rows) nblk = max_rows;
    if (nblk < 1) nblk = 1;

    float* partial = (float*)d_ws;

    yolo_partial_kernel<<<nblk, 256, 0, stream>>>(pred, tbox, tcls, obj, partial, M, ntiles);
    yolo_final_kernel<<<1, 256, 0, stream>>>(pred, tbox, partial, out, nblk, 1.f / (float)N);
}